// Round 8
// baseline (2555.304 us; speedup 1.0000x reference)
//
#include <hip/hip_runtime.h>

typedef unsigned short u16;
typedef unsigned int u32;

__device__ __forceinline__ float b2f(u16 v) { return __uint_as_float((u32)v << 16); }
__device__ __forceinline__ float lopart(u32 u) { return __uint_as_float(u << 16); }
__device__ __forceinline__ float hipart(u32 u) { return __uint_as_float(u & 0xffff0000u); }
__device__ __forceinline__ u16 f2b(float f) {
  u32 u = __float_as_uint(f);
  u32 r = u + 0x7fffu + ((u >> 16) & 1u);
  return (u16)(r >> 16);
}
__device__ __forceinline__ u32 pk2(float a, float b) {
  return (u32)f2b(a) | ((u32)f2b(b) << 16);
}

struct Ptrs { const void* p[29]; };

// ---------------- K-2: dtype flag (bn1_g[0]: bf16 pair 0x3F803F80 vs fp32 0x3F800000) ----------------
__global__ void k_resolve(const void* __restrict__ g1, int* __restrict__ dtf) {
  if (threadIdx.x == 0) {
    u32 w = *(const u32*)g1;
    *dtf = ((w & 0xffffu) != 0) ? 1 : 0;
  }
}

// ---------------- K-1: convert A + all weights to fp32 (C-order identity; dict order) ----------------
__global__ __launch_bounds__(256) void k_cvt(Ptrs ps, const int* __restrict__ dtf,
                                             float* __restrict__ Af, float* __restrict__ Wf) {
  bool BF = *dtf != 0;
  int i = blockIdx.x * 256 + threadIdx.x;
  if (i < 250000) {
    const void* pA = ps.p[1];
    Af[i] = BF ? b2f(((const u16*)pA)[i]) : ((const float*)pA)[i];
    return;
  }
  int j = i - 250000;
  if (j >= 65322) return;
  const int SZ[27] = {1024,32,2048,64,12288,64,12288,64,4096,64,4096,64,2048,32,
                      10240,64,60,6,32,500,16000,36,36,6,6,32,32};
  int t = 0, off = 0;
#pragma unroll
  for (int k = 0; k < 27; ++k) {
    if (t == k && j >= off + SZ[k]) { off += SZ[k]; t = k + 1; }
  }
  const void* src = ps.p[2 + t];
  int l = j - off;
  Wf[j] = BF ? b2f(((const u16*)src)[l]) : ((const float*)src)[l];
}

// ---------------- K-0b: x -> fp32 (identity C-order) ----------------
__global__ __launch_bounds__(256) void k_cvtx(const void* __restrict__ x, const int* __restrict__ dtf,
                                              float* __restrict__ xf) {
  bool BF = *dtf != 0;
  int i = blockIdx.x * 256 + threadIdx.x;
  if (i < 2560000) xf[i] = BF ? b2f(((const u16*)x)[i]) : ((const float*)x)[i];
}

// ---------------- K0: A2 = A @ A  (fp32) ----------------
__global__ __launch_bounds__(256) void k_a2(const float* __restrict__ Af, float* __restrict__ A2) {
  __shared__ float Arow[8][500];
  int tid = threadIdx.x;
  int j = blockIdx.x * 256 + tid;
  int i0 = blockIdx.y * 8;
  for (int i = tid; i < 4000; i += 256) {
    int r = i / 500, kk = i - r * 500;
    int ii = i0 + r; if (ii > 499) ii = 499;
    Arow[r][kk] = Af[ii * 500 + kk];
  }
  __syncthreads();
  if (j >= 500) return;
  float acc[8];
#pragma unroll
  for (int ii = 0; ii < 8; ++ii) acc[ii] = 0.f;
  for (int k = 0; k < 500; ++k) {
    float akj = Af[k * 500 + j];
#pragma unroll
    for (int ii = 0; ii < 8; ++ii) acc[ii] += Arow[ii][k] * akj;
  }
#pragma unroll
  for (int ii = 0; ii < 8; ++ii)
    if (i0 + ii < 500) A2[(i0 + ii) * 500 + j] = acc[ii];
}

// ---------------- K1: frontend  x -> h3x (B,T,N,32) + res6 ----------------
__global__ __launch_bounds__(256) void k_front(
    const float* __restrict__ xf,
    const float* __restrict__ c1W, const float* __restrict__ c1B,
    const float* __restrict__ te1W, const float* __restrict__ te1B,
    const float* __restrict__ qW, const float* __restrict__ qB,
    const float* __restrict__ kW, const float* __restrict__ kB,
    const float* __restrict__ lvW, const float* __restrict__ lvB,
    const float* __restrict__ loW, const float* __restrict__ loB,
    const float* __restrict__ te2W, const float* __restrict__ te2B,
    float* __restrict__ h3x, float* __restrict__ res6)
{
  __shared__ u32 qk[12288];          // packed (Wq | Wk<<16) bf16 pairs
  __shared__ float xv[32][10];
  __shared__ float h1b[64][10];
  __shared__ float qbuf[64][10];
  __shared__ float kbuf[64][10];
  __shared__ float vbuf[64][10];
  __shared__ float scb[800];
  int tid = threadIdx.x;
  int b = blockIdx.y;
  int n0 = blockIdx.x * 8;
  for (int e = tid; e < 12288; e += 256)
    qk[e] = pk2(qW[e], kW[e]);
  __syncthreads();
  int nend = n0 + 8; if (nend > 500) nend = 500;
  for (int n = n0; n < nend; ++n) {
    for (int i = tid; i < 320; i += 256) {
      int c = i / 10, t = i - c * 10;
      xv[c][t] = xf[((b * 32 + c) * 500 + n) * 10 + t];
    }
    __syncthreads();
    if (tid < 192) {
      int c = tid / 6, t6 = tid - c * 6, t = t6 + 4;
      float a = c1B[c];
      for (int i = 0; i < 32; ++i) a += c1W[c * 32 + i] * xv[i][t];
      res6[((b * 32 + c) * 500 + n) * 6 + t6] = a;
    }
    for (int idx = tid; idx < 640; idx += 256) {
      int o = idx / 10, t = idx - o * 10;
      float a = te1B[o];
      for (int c = 0; c < 32; ++c) a += te1W[o * 32 + c] * xv[c][t];
      h1b[o][t] = a;
    }
    __syncthreads();
    for (int idx = tid; idx < 640; idx += 256) {
      int o = idx / 10, t = idx - o * 10;
      float aq = qB[o], ak = kB[o], av = lvB[o];
      int e = o * 192;
      for (int i = 0; i < 64; ++i, e += 3) {
        float hm = (t > 0) ? h1b[i][t - 1] : 0.f;
        float h0 = h1b[i][t];
        float hp = (t < 9) ? h1b[i][t + 1] : 0.f;
        u32 u0 = qk[e], u1 = qk[e + 1], u2 = qk[e + 2];
        aq += lopart(u0) * hm + lopart(u1) * h0 + lopart(u2) * hp;
        ak += hipart(u0) * hm + hipart(u1) * h0 + hipart(u2) * hp;
        av += lvW[o * 64 + i] * h0;
      }
      qbuf[o][t] = aq; kbuf[o][t] = ak; vbuf[o][t] = av;
    }
    __syncthreads();
    for (int idx = tid; idx < 800; idx += 256) {
      int h = idx / 100, r = (idx / 10) % 10, s = idx - (idx / 10) * 10;
      float a = 0.f;
#pragma unroll
      for (int d = 0; d < 8; ++d) a += qbuf[h * 8 + d][r] * kbuf[h * 8 + d][s];
      scb[idx] = a * 0.35355339059327373f;
    }
    __syncthreads();
    if (tid < 80) {
      float* row = scb + tid * 10;
      float mx = row[0];
#pragma unroll
      for (int s = 1; s < 10; ++s) mx = fmaxf(mx, row[s]);
      float tot = 0.f;
#pragma unroll
      for (int s = 0; s < 10; ++s) { float e2 = expf(row[s] - mx); row[s] = e2; tot += e2; }
      float inv = 1.f / tot;
#pragma unroll
      for (int s = 0; s < 10; ++s) row[s] *= inv;
    }
    __syncthreads();
    for (int idx = tid; idx < 640; idx += 256) {
      int j = idx / 10, t = idx - j * 10, h = j >> 3;
      float a = 0.f;
#pragma unroll
      for (int s = 0; s < 10; ++s) a += scb[h * 100 + t * 10 + s] * vbuf[j][s];
      qbuf[j][t] = a;
    }
    __syncthreads();
    for (int idx = tid; idx < 640; idx += 256) {
      int o = idx / 10, t = idx - o * 10;
      float a = loB[o];
      for (int j = 0; j < 64; ++j) a += loW[o * 64 + j] * qbuf[j][t];
      kbuf[o][t] = a;
    }
    __syncthreads();
    for (int idx = tid; idx < 320; idx += 256) {
      int t = idx >> 5, c = idx & 31;
      float a = te2B[c];
      for (int j = 0; j < 64; ++j) a += te2W[c * 64 + j] * kbuf[j][t];
      h3x[((b * 10 + t) * 500 + n) * 32 + c] = a;
    }
    __syncthreads();
  }
}

// ---------------- K2: z1 = A @ xt, z2 = A2 @ xt ----------------
__global__ __launch_bounds__(256) void k_z12n(const float* __restrict__ h3x,
    const float* __restrict__ Af, const float* __restrict__ A2,
    float* __restrict__ z1x, float* __restrict__ z2x) {
  int bt = blockIdx.x;
  int w = blockIdx.y * 8 + (threadIdx.x >> 5);
  int c = threadIdx.x & 31;
  if (w >= 500) return;
  const float* src = h3x + bt * 16000;
  float a1 = 0.f, a2 = 0.f;
  for (int v = 0; v < 500; ++v) {
    float xv = src[v * 32 + c];
    a1 += Af[w * 500 + v] * xv;
    a2 += A2[w * 500 + v] * xv;
  }
  z1x[(bt * 500 + w) * 32 + c] = a1;
  z2x[(bt * 500 + w) * 32 + c] = a2;
}

// ---------------- K3: out = softmax(keys @ keys^T / sqrt(32)) @ vals ----------------
__global__ __launch_bounds__(256) void k_attn(const float* __restrict__ keys,
                                              const float* __restrict__ vals,
                                              float* __restrict__ outp) {
  __shared__ u32 vl[8000];
  __shared__ float xr[32];
  __shared__ float sarr[500];
  __shared__ float wred[4];
  __shared__ float prod[8][33];
  int tid = threadIdx.x, bt = blockIdx.x, r0 = blockIdx.y * 50;
  const float* kb = keys + bt * 16000;
  const float* vb = vals + bt * 16000;
  for (int i = tid; i < 8000; i += 256) {
    float2 g = *(const float2*)(vb + i * 2);
    vl[i] = pk2(g.x, g.y);
  }
  __syncthreads();
  for (int rl = 0; rl < 50; ++rl) {
    int r = r0 + rl;
    if (tid < 32) xr[tid] = kb[r * 32 + tid];
    __syncthreads();
    float s0, s1 = -1e30f;
    {
      float s = 0.f;
      const float* kp = kb + tid * 32;
      for (int c = 0; c < 32; ++c) s += xr[c] * kp[c];
      s0 = s * 0.17677669529663687f;
      if (tid + 256 < 500) {
        float s2 = 0.f;
        const float* kp2 = kb + (tid + 256) * 32;
        for (int c = 0; c < 32; ++c) s2 += xr[c] * kp2[c];
        s1 = s2 * 0.17677669529663687f;
      }
    }
    float v = fmaxf(s0, s1);
    for (int off = 32; off; off >>= 1) v = fmaxf(v, __shfl_xor(v, off));
    if ((tid & 63) == 0) wred[tid >> 6] = v;
    __syncthreads();
    float mx = fmaxf(fmaxf(wred[0], wred[1]), fmaxf(wred[2], wred[3]));
    __syncthreads();
    float e0 = expf(s0 - mx);
    float e1 = (tid + 256 < 500) ? expf(s1 - mx) : 0.f;
    sarr[tid] = e0;
    if (tid + 256 < 500) sarr[tid + 256] = e1;
    float ls = e0 + e1;
    for (int off = 32; off; off >>= 1) ls += __shfl_xor(ls, off);
    if ((tid & 63) == 0) wred[tid >> 6] = ls;
    __syncthreads();
    float inv = 1.f / (wred[0] + wred[1] + wred[2] + wred[3]);
    int grp = tid >> 5, c = tid & 31;
    int pj = c >> 1; bool odd = (c & 1) != 0;
    float acc = 0.f;
    for (int m = grp; m < 500; m += 8) {
      u32 u = vl[m * 16 + pj];
      acc += sarr[m] * (odd ? hipart(u) : lopart(u));
    }
    prod[grp][c] = acc;
    __syncthreads();
    if (grp == 0) {
      float a = 0.f;
#pragma unroll
      for (int g = 0; g < 8; ++g) a += prod[g][c];
      outp[(bt * 500 + r) * 32 + c] = a * inv;
    }
    __syncthreads();
  }
}

// ---------------- K4: mlp + gate + ct1 -> g2 ----------------
__global__ __launch_bounds__(256) void k_mlp(
    const float* __restrict__ h3x, const float* __restrict__ z1x, const float* __restrict__ z2x,
    const float* __restrict__ z3x, const float* __restrict__ z4x,
    const float* __restrict__ mlpW, const float* __restrict__ mlpB,
    const float* __restrict__ ct1W, const float* __restrict__ ct1B,
    float* __restrict__ g2w)
{
  __shared__ float Wm[10240];
  __shared__ float cat[32][161];
  __shared__ float ct1l[60];
  __shared__ float ct1bl[6];
  __shared__ float mbl[64];
  int tid = threadIdx.x;
  int b = blockIdx.y, n0 = blockIdx.x * 32;
  int nn = 500 - n0; if (nn > 32) nn = 32;
  for (int i = tid; i < 10240; i += 256) Wm[i] = mlpW[i];
  if (tid < 60) ct1l[tid] = ct1W[tid];
  if (tid < 6)  ct1bl[tid] = ct1B[tid];
  if (tid < 64) mbl[tid] = mlpB[tid];
  __syncthreads();
  int nl = tid & 31, slot = tid >> 5;
  bool act = nl < nn;
  int n = n0 + nl;
  float g2r[4][6];
#pragma unroll
  for (int k = 0; k < 4; ++k)
#pragma unroll
    for (int s = 0; s < 6; ++s) g2r[k][s] = 0.f;
  for (int t = 0; t < 10; ++t) {
    int rowbase = (b * 10 + t) * 500 + n0;
#pragma unroll
    for (int seg = 0; seg < 5; ++seg) {
      const float* sp = seg == 0 ? h3x : seg == 1 ? z1x : seg == 2 ? z2x : seg == 3 ? z3x : z4x;
      for (int i = tid; i < 1024; i += 256) {
        int nb = i >> 5, cc = i & 31;
        cat[nb][seg * 32 + cc] = (nb < nn) ? sp[(rowbase + nb) * 32 + cc] : 0.f;
      }
    }
    __syncthreads();
    if (act) {
      float hc[8];
#pragma unroll
      for (int k = 0; k < 8; ++k) hc[k] = mbl[slot + 8 * k];
      for (int cch = 0; cch < 160; ++cch) {
        float xvv = cat[nl][cch];
#pragma unroll
        for (int k = 0; k < 8; ++k) hc[k] += Wm[(slot + 8 * k) * 160 + cch] * xvv;
      }
#pragma unroll
      for (int k = 0; k < 4; ++k) {
        float gk = tanhf(hc[k]) * (1.f / (1.f + expf(-hc[k + 4])));
#pragma unroll
        for (int s = 0; s < 6; ++s) g2r[k][s] += gk * ct1l[s * 10 + t];
      }
    }
    __syncthreads();
  }
  if (act) {
#pragma unroll
    for (int k = 0; k < 4; ++k) {
      int cc = slot + 8 * k;
      int base = ((b * 32 + cc) * 500 + n) * 6;
#pragma unroll
      for (int s = 0; s < 6; ++s) g2w[base + s] = g2r[k][s] + ct1bl[s];
    }
  }
}

// ---------------- K4b: f1 ----------------
__global__ __launch_bounds__(256) void k_f1n(const float* __restrict__ g2w,
                                             const float* __restrict__ tc1W,
                                             float* __restrict__ f1w) {
  int i = blockIdx.x * 256 + threadIdx.x;
  if (i >= 48000) return;
  int b = i / 3000, rem = i - b * 3000, s = rem / 500, n = rem - s * 500;
  float a = 0.f;
  for (int c = 0; c < 32; ++c) a += g2w[((b * 32 + c) * 500 + n) * 6 + s] * tc1W[c];
  f1w[(b * 6 + s) * 500 + n] = a;
}

// ---------------- K5a: f2 ----------------
__global__ __launch_bounds__(64) void k_f2(const float* __restrict__ g2w,
                                           const float* __restrict__ c2W, float* __restrict__ f2w) {
  int b = blockIdx.x >> 5, c = blockIdx.x & 31, lane = threadIdx.x;
  float acc[6];
#pragma unroll
  for (int t = 0; t < 6; ++t) acc[t] = 0.f;
  for (int n = lane; n < 500; n += 64) {
    float w = c2W[n];
    const float* gp = g2w + ((b * 32 + c) * 500 + n) * 6;
#pragma unroll
    for (int t = 0; t < 6; ++t) acc[t] += w * gp[t];
  }
#pragma unroll
  for (int t = 0; t < 6; ++t)
    for (int off = 32; off; off >>= 1) acc[t] += __shfl_xor(acc[t], off);
  if (lane == 0) {
#pragma unroll
    for (int t = 0; t < 6; ++t) f2w[(b * 32 + c) * 6 + t] = acc[t];
  }
}

// ---------------- K5b: per-b TATT ----------------
__global__ __launch_bounds__(256) void k_tatt(
    const float* __restrict__ f1w, const float* __restrict__ tatw,
    const float* __restrict__ f2w, const float* __restrict__ tatb, const float* __restrict__ tatv,
    float* __restrict__ lg2w)
{
  __shared__ float mid[192];
  __shared__ float lgt[36];
  int b = blockIdx.x, tid = threadIdx.x;
  if (tid < 192) {
    int t = tid >> 5, c = tid & 31;
    float a = 0.f;
    const float* f1p = f1w + (b * 6 + t) * 500;
    for (int n = 0; n < 500; ++n) a += f1p[n] * tatw[n * 32 + c];
    mid[t * 32 + c] = a;
  }
  __syncthreads();
  if (tid < 36) {
    int t = tid / 6, s = tid - t * 6;
    float a = tatb[t * 6 + s];
    for (int c = 0; c < 32; ++c) a += mid[t * 32 + c] * f2w[(b * 32 + c) * 6 + s];
    lgt[t * 6 + s] = 1.f / (1.f + expf(-a));
  }
  __syncthreads();
  if (tid < 36) {
    int p = tid / 6, s = tid - p * 6;
    float a = 0.f;
#pragma unroll
    for (int t2 = 0; t2 < 6; ++t2) a += tatv[p * 6 + t2] * lgt[t2 * 6 + s];
    lg2w[(b * 6 + p) * 6 + s] = a;
  }
}

// ---------------- K5c: BN1 + softmax -> Tc ----------------
__global__ __launch_bounds__(128) void k_coefs(const float* __restrict__ lg2w,
    const float* __restrict__ bn1g, const float* __restrict__ bn1b, float* __restrict__ tcw) {
  __shared__ float mu[6], iv[6], gg[6], bb[6];
  int tid = threadIdx.x;
  if (tid < 6) {
    float s = 0.f, sq = 0.f;
    for (int b = 0; b < 16; ++b)
      for (int q = 0; q < 6; ++q) {
        float v = lg2w[(b * 6 + q) * 6 + tid];
        s += v; sq += v * v;
      }
    float m = s / 96.f;
    mu[tid] = m;
    iv[tid] = rsqrtf(sq / 96.f - m * m + 1e-5f);
    gg[tid] = bn1g[tid]; bb[tid] = bn1b[tid];
  }
  __syncthreads();
  for (int idx = tid; idx < 96; idx += 128) {
    int b = idx / 6, q = idx - b * 6;
    float v[6], mx = -1e30f;
#pragma unroll
    for (int l = 0; l < 6; ++l) {
      v[l] = (lg2w[(b * 6 + q) * 6 + l] - mu[l]) * iv[l] * gg[l] + bb[l];
      mx = fmaxf(mx, v[l]);
    }
    float tot = 0.f;
#pragma unroll
    for (int l = 0; l < 6; ++l) { v[l] = expf(v[l] - mx); tot += v[l]; }
    float inv = 1.f / tot;
#pragma unroll
    for (int l = 0; l < 6; ++l) tcw[(b * 6 + l) * 6 + q] = v[l] * inv;
  }
}

// ---------------- K6a: xo = leaky(g2@Tc)+res6, per-c sum/sumsq ----------------
__global__ __launch_bounds__(256) void k_xo(const float* __restrict__ g2w,
    const float* __restrict__ res6, const float* __restrict__ tcw,
    float* __restrict__ xow, float* __restrict__ stats) {
  __shared__ float Tcl[36];
  __shared__ float redS[32][8], redQ[32][8];
  int b = blockIdx.x, chunk = blockIdx.y, tid = threadIdx.x;
  if (tid < 36) Tcl[tid] = tcw[b * 36 + tid];
  __syncthreads();
  int c = tid & 31, sub = tid >> 5;
  int n0 = chunk * 50;
  float s = 0.f, sq = 0.f;
  for (int idx = sub; idx < 300; idx += 8) {
    int nl = idx / 6, q = idx - nl * 6;
    int n = n0 + nl;
    int base = ((b * 32 + c) * 500 + n) * 6;
    const float* gp = g2w + base;
    float xv = 0.f;
#pragma unroll
    for (int l = 0; l < 6; ++l) xv += gp[l] * Tcl[l * 6 + q];
    xv = xv > 0.f ? xv : 0.01f * xv;
    xv += res6[base + q];
    xow[base + q] = xv;
    s += xv; sq += xv * xv;
  }
  redS[c][sub] = s; redQ[c][sub] = sq;
  __syncthreads();
  if (sub == 0) {
    float ts = 0.f, tq = 0.f;
#pragma unroll
    for (int k = 0; k < 8; ++k) { ts += redS[c][k]; tq += redQ[c][k]; }
    atomicAdd(&stats[c], ts);
    atomicAdd(&stats[32 + c], tq);
  }
}

// ---------------- K6b: BN2 normalize -> FP32 out (reference output dtype is float32) ----------------
__global__ __launch_bounds__(256) void k_out(const float* __restrict__ xow,
    const float* __restrict__ stats, const float* __restrict__ g2c, const float* __restrict__ b2c,
    float* __restrict__ out) {
  int base = (blockIdx.x * 256 + threadIdx.x) * 4;
#pragma unroll
  for (int k = 0; k < 4; ++k) {
    int i = base + k;
    int c = (i / 3000) & 31;
    float m = stats[c] * (1.f / 48000.f);
    float var = stats[32 + c] * (1.f / 48000.f) - m * m;
    out[i] = (xow[i] - m) * rsqrtf(var + 1e-5f) * g2c[c] + b2c[c];
  }
}

extern "C" void kernel_launch(void* const* d_in, const int* in_sizes, int n_in,
                              void* d_out, int out_size, void* d_ws, size_t ws_size,
                              hipStream_t stream)
{
  (void)in_sizes; (void)out_size;

  float* ws = (float*)d_ws;
  float* Af   = ws;                 // 250,000
  float* Wf   = Af + 250000;        // 65,536 (65,322 used)
  float* A2   = Wf + 65536;         // 250,000
  float* h3x  = A2 + 250000;        // 2,560,000 (B,T,N,32)
  float* z1x  = h3x + 2560000;
  float* z2x  = z1x + 2560000;
  float* z3x  = z2x + 2560000;
  float* z4x  = z3x + 2560000;
  float* res6 = z4x + 2560000;      // 1,536,000
  float* g2w  = res6 + 1536000;     // 1,536,000
  float* f1w  = g2w + 1536000;      // 48,000
  float* f2w  = f1w + 48000;        // 3,072
  float* lg2w = f2w + 3072;         // 576
  float* tcw  = lg2w + 576;         // 576
  float* stats= tcw + 576;          // 64
  int*   dtf  = (int*)(stats + 64); // 1 int
  float* xf   = z4x;                // x fp32 overlay: dead after k_front, before k_attn#2
  float* xow  = z1x;                // reuse z1 region after k_mlp
  if (ws_size < (size_t)16489952 * sizeof(float)) return;  // workspace guard

  // converted-weight offsets inside Wf (cumulative over dict inputs 2..28)
  const float* c1W  = Wf + 0;
  const float* c1B  = Wf + 1024;
  const float* te1W = Wf + 1056;
  const float* te1B = Wf + 3104;
  const float* qW   = Wf + 3168;
  const float* qB   = Wf + 15456;
  const float* kW   = Wf + 15520;
  const float* kB   = Wf + 27808;
  const float* lvW  = Wf + 27872;
  const float* lvB  = Wf + 31968;
  const float* loW  = Wf + 32032;
  const float* loB  = Wf + 36128;
  const float* te2W = Wf + 36192;
  const float* te2B = Wf + 38240;
  const float* mlpW = Wf + 38272;
  const float* mlpB = Wf + 48512;
  const float* ct1W = Wf + 48576;
  const float* ct1B = Wf + 48636;
  const float* tc1W = Wf + 48642;
  const float* tc2W = Wf + 48674;
  const float* tatw = Wf + 49174;
  const float* tatb = Wf + 65174;
  const float* tatv = Wf + 65210;
  const float* bn1g = Wf + 65246;
  const float* bn1b = Wf + 65252;
  const float* bn2g = Wf + 65258;
  const float* bn2b = Wf + 65290;

  Ptrs ps;
  for (int i = 0; i < 29; ++i) ps.p[i] = (i < n_in) ? d_in[i] : d_in[0];

  hipMemsetAsync(stats, 0, 64 * sizeof(float), stream);
  k_resolve<<<dim3(1),     64, 0, stream>>>(ps.p[25], dtf);
  k_cvt  <<<dim3(1232),    256, 0, stream>>>(ps, dtf, Af, Wf);
  k_cvtx <<<dim3(10000),   256, 0, stream>>>(ps.p[0], dtf, xf);
  k_a2   <<<dim3(2, 63),   256, 0, stream>>>(Af, A2);
  k_front<<<dim3(63, 16),  256, 0, stream>>>(xf, c1W, c1B, te1W, te1B,
                                             qW, qB, kW, kB, lvW, lvB, loW, loB,
                                             te2W, te2B, h3x, res6);
  k_z12n <<<dim3(160, 63), 256, 0, stream>>>(h3x, Af, A2, z1x, z2x);
  k_attn <<<dim3(160, 10), 256, 0, stream>>>(h3x, h3x, z3x);
  k_attn <<<dim3(160, 10), 256, 0, stream>>>(h3x, z3x, z4x);
  k_mlp  <<<dim3(16, 16),  256, 0, stream>>>(h3x, z1x, z2x, z3x, z4x, mlpW, mlpB,
                                             ct1W, ct1B, g2w);
  k_f1n  <<<dim3(188),     256, 0, stream>>>(g2w, tc1W, f1w);
  k_f2   <<<dim3(512),      64, 0, stream>>>(g2w, tc2W, f2w);
  k_tatt <<<dim3(16),      256, 0, stream>>>(f1w, tatw, f2w, tatb, tatv, lg2w);
  k_coefs<<<dim3(1),       128, 0, stream>>>(lg2w, bn1g, bn1b, tcw);
  k_xo   <<<dim3(16, 10),  256, 0, stream>>>(g2w, res6, tcw, xow, stats);
  k_out  <<<dim3(1500),    256, 0, stream>>>(xow, stats, bn2g, bn2b, (float*)d_out);
}

// Round 9
// 1484.783 us; speedup vs baseline: 1.7210x; 1.7210x over previous
//
#include <hip/hip_runtime.h>

typedef unsigned short u16;
typedef unsigned int u32;

__device__ __forceinline__ float b2f(u16 v) { return __uint_as_float((u32)v << 16); }
__device__ __forceinline__ float lopart(u32 u) { return __uint_as_float(u << 16); }
__device__ __forceinline__ float hipart(u32 u) { return __uint_as_float(u & 0xffff0000u); }
__device__ __forceinline__ u16 f2b(float f) {
  u32 u = __float_as_uint(f);
  u32 r = u + 0x7fffu + ((u >> 16) & 1u);
  return (u16)(r >> 16);
}
__device__ __forceinline__ u32 pk2(float a, float b) {
  return (u32)f2b(a) | ((u32)f2b(b) << 16);
}

struct Ptrs { const void* p[29]; };

typedef __attribute__((ext_vector_type(8))) short short8;
typedef __attribute__((ext_vector_type(4))) float floatx4;

// ---------------- K-2: dtype flag (bn1_g[0]: bf16 pair 0x3F803F80 vs fp32 0x3F800000) ----------------
__global__ void k_resolve(const void* __restrict__ g1, int* __restrict__ dtf) {
  if (threadIdx.x == 0) {
    u32 w = *(const u32*)g1;
    *dtf = ((w & 0xffffu) != 0) ? 1 : 0;
  }
}

// ---------------- K-1: convert A + all weights to fp32 (C-order identity; dict order) ----------------
__global__ __launch_bounds__(256) void k_cvt(Ptrs ps, const int* __restrict__ dtf,
                                             float* __restrict__ Af, float* __restrict__ Wf) {
  bool BF = *dtf != 0;
  int i = blockIdx.x * 256 + threadIdx.x;
  if (i < 250000) {
    const void* pA = ps.p[1];
    Af[i] = BF ? b2f(((const u16*)pA)[i]) : ((const float*)pA)[i];
    return;
  }
  int j = i - 250000;
  if (j >= 65322) return;
  const int SZ[27] = {1024,32,2048,64,12288,64,12288,64,4096,64,4096,64,2048,32,
                      10240,64,60,6,32,500,16000,36,36,6,6,32,32};
  int t = 0, off = 0;
#pragma unroll
  for (int k = 0; k < 27; ++k) {
    if (t == k && j >= off + SZ[k]) { off += SZ[k]; t = k + 1; }
  }
  const void* src = ps.p[2 + t];
  int l = j - off;
  Wf[j] = BF ? b2f(((const u16*)src)[l]) : ((const float*)src)[l];
}

// ---------------- K-0b: x -> fp32 (identity C-order) ----------------
__global__ __launch_bounds__(256) void k_cvtx(const void* __restrict__ x, const int* __restrict__ dtf,
                                              float* __restrict__ xf) {
  bool BF = *dtf != 0;
  int i = blockIdx.x * 256 + threadIdx.x;
  if (i < 2560000) xf[i] = BF ? b2f(((const u16*)x)[i]) : ((const float*)x)[i];
}

// ---------------- K0: A2 = A @ A  (fp32) ----------------
__global__ __launch_bounds__(256) void k_a2(const float* __restrict__ Af, float* __restrict__ A2) {
  __shared__ float Arow[8][500];
  int tid = threadIdx.x;
  int j = blockIdx.x * 256 + tid;
  int i0 = blockIdx.y * 8;
  for (int i = tid; i < 4000; i += 256) {
    int r = i / 500, kk = i - r * 500;
    int ii = i0 + r; if (ii > 499) ii = 499;
    Arow[r][kk] = Af[ii * 500 + kk];
  }
  __syncthreads();
  if (j >= 500) return;
  float acc[8];
#pragma unroll
  for (int ii = 0; ii < 8; ++ii) acc[ii] = 0.f;
  for (int k = 0; k < 500; ++k) {
    float akj = Af[k * 500 + j];
#pragma unroll
    for (int ii = 0; ii < 8; ++ii) acc[ii] += Arow[ii][k] * akj;
  }
#pragma unroll
  for (int ii = 0; ii < 8; ++ii)
    if (i0 + ii < 500) A2[(i0 + ii) * 500 + j] = acc[ii];
}

// ---------------- K1: frontend  x -> h3x (B,T,N,32) + res6 ----------------
__global__ __launch_bounds__(256) void k_front(
    const float* __restrict__ xf,
    const float* __restrict__ c1W, const float* __restrict__ c1B,
    const float* __restrict__ te1W, const float* __restrict__ te1B,
    const float* __restrict__ qW, const float* __restrict__ qB,
    const float* __restrict__ kW, const float* __restrict__ kB,
    const float* __restrict__ lvW, const float* __restrict__ lvB,
    const float* __restrict__ loW, const float* __restrict__ loB,
    const float* __restrict__ te2W, const float* __restrict__ te2B,
    float* __restrict__ h3x, float* __restrict__ res6)
{
  __shared__ u32 qk[12288];          // packed (Wq | Wk<<16) bf16 pairs
  __shared__ float xv[32][10];
  __shared__ float h1b[64][10];
  __shared__ float qbuf[64][10];
  __shared__ float kbuf[64][10];
  __shared__ float vbuf[64][10];
  __shared__ float scb[800];
  int tid = threadIdx.x;
  int b = blockIdx.y;
  int n0 = blockIdx.x * 8;
  for (int e = tid; e < 12288; e += 256)
    qk[e] = pk2(qW[e], kW[e]);
  __syncthreads();
  int nend = n0 + 8; if (nend > 500) nend = 500;
  for (int n = n0; n < nend; ++n) {
    for (int i = tid; i < 320; i += 256) {
      int c = i / 10, t = i - c * 10;
      xv[c][t] = xf[((b * 32 + c) * 500 + n) * 10 + t];
    }
    __syncthreads();
    if (tid < 192) {
      int c = tid / 6, t6 = tid - c * 6, t = t6 + 4;
      float a = c1B[c];
      for (int i = 0; i < 32; ++i) a += c1W[c * 32 + i] * xv[i][t];
      res6[((b * 32 + c) * 500 + n) * 6 + t6] = a;
    }
    for (int idx = tid; idx < 640; idx += 256) {
      int o = idx / 10, t = idx - o * 10;
      float a = te1B[o];
      for (int c = 0; c < 32; ++c) a += te1W[o * 32 + c] * xv[c][t];
      h1b[o][t] = a;
    }
    __syncthreads();
    for (int idx = tid; idx < 640; idx += 256) {
      int o = idx / 10, t = idx - o * 10;
      float aq = qB[o], ak = kB[o], av = lvB[o];
      int e = o * 192;
      for (int i = 0; i < 64; ++i, e += 3) {
        float hm = (t > 0) ? h1b[i][t - 1] : 0.f;
        float h0 = h1b[i][t];
        float hp = (t < 9) ? h1b[i][t + 1] : 0.f;
        u32 u0 = qk[e], u1 = qk[e + 1], u2 = qk[e + 2];
        aq += lopart(u0) * hm + lopart(u1) * h0 + lopart(u2) * hp;
        ak += hipart(u0) * hm + hipart(u1) * h0 + hipart(u2) * hp;
        av += lvW[o * 64 + i] * h0;
      }
      qbuf[o][t] = aq; kbuf[o][t] = ak; vbuf[o][t] = av;
    }
    __syncthreads();
    for (int idx = tid; idx < 800; idx += 256) {
      int h = idx / 100, r = (idx / 10) % 10, s = idx - (idx / 10) * 10;
      float a = 0.f;
#pragma unroll
      for (int d = 0; d < 8; ++d) a += qbuf[h * 8 + d][r] * kbuf[h * 8 + d][s];
      scb[idx] = a * 0.35355339059327373f;
    }
    __syncthreads();
    if (tid < 80) {
      float* row = scb + tid * 10;
      float mx = row[0];
#pragma unroll
      for (int s = 1; s < 10; ++s) mx = fmaxf(mx, row[s]);
      float tot = 0.f;
#pragma unroll
      for (int s = 0; s < 10; ++s) { float e2 = expf(row[s] - mx); row[s] = e2; tot += e2; }
      float inv = 1.f / tot;
#pragma unroll
      for (int s = 0; s < 10; ++s) row[s] *= inv;
    }
    __syncthreads();
    for (int idx = tid; idx < 640; idx += 256) {
      int j = idx / 10, t = idx - j * 10, h = j >> 3;
      float a = 0.f;
#pragma unroll
      for (int s = 0; s < 10; ++s) a += scb[h * 100 + t * 10 + s] * vbuf[j][s];
      qbuf[j][t] = a;
    }
    __syncthreads();
    for (int idx = tid; idx < 640; idx += 256) {
      int o = idx / 10, t = idx - o * 10;
      float a = loB[o];
      for (int j = 0; j < 64; ++j) a += loW[o * 64 + j] * qbuf[j][t];
      kbuf[o][t] = a;
    }
    __syncthreads();
    for (int idx = tid; idx < 320; idx += 256) {
      int t = idx >> 5, c = idx & 31;
      float a = te2B[c];
      for (int j = 0; j < 64; ++j) a += te2W[c * 64 + j] * kbuf[j][t];
      h3x[((b * 10 + t) * 500 + n) * 32 + c] = a;
    }
    __syncthreads();
  }
}

// ---------------- K2: z1 = A @ xt, z2 = A2 @ xt ----------------
__global__ __launch_bounds__(256) void k_z12n(const float* __restrict__ h3x,
    const float* __restrict__ Af, const float* __restrict__ A2,
    float* __restrict__ z1x, float* __restrict__ z2x) {
  int bt = blockIdx.x;
  int w = blockIdx.y * 8 + (threadIdx.x >> 5);
  int c = threadIdx.x & 31;
  if (w >= 500) return;
  const float* src = h3x + bt * 16000;
  float a1 = 0.f, a2 = 0.f;
  for (int v = 0; v < 500; ++v) {
    float xv = src[v * 32 + c];
    a1 += Af[w * 500 + v] * xv;
    a2 += A2[w * 500 + v] * xv;
  }
  z1x[(bt * 500 + w) * 32 + c] = a1;
  z2x[(bt * 500 + w) * 32 + c] = a2;
}

// ---------------- K3: MFMA fused attention: out = softmax(K K^T / sqrt(32)) @ V ----------------
// Block = (bt, 64-row chunk), 4 waves; each wave computes a 16-row strip.
// Keys staged once to LDS as XOR-swizzled bf16 pairs (conflict-free A/B frag reads).
// S strip: 32 MFMAs (16x16x32, K=32=D); softmax in registers; P->A-layout via 1KB/wave
// private LDS chunk; PV: 32 MFMAs, V read from global fp32 (truncate to bf16).
__global__ __launch_bounds__(256, 2) void k_attn2(const float* __restrict__ keys,
                                                  const float* __restrict__ vals,
                                                  float* __restrict__ outp) {
  __shared__ u32 xls[8192];        // 512 rows x 16 u32 bf16-pairs, swizzled (32 KB)
  __shared__ u32 pch[4][272];      // per-wave P chunk: 16 x 17 u32 (4.25 KB)
  int tid = threadIdx.x, bt = blockIdx.x;
  const float* kb = keys + bt * 16000;
  for (int i = tid; i < 8192; i += 256) {
    int r = i >> 4, cu = i & 15;
    u32 u = 0;
    if (r < 500) {
      float2 g = *(const float2*)(kb + r * 32 + cu * 2);
      u = pk2(g.x, g.y);
    }
    xls[(r << 4) | (cu ^ (r & 15))] = u;
  }
  __syncthreads();
  int lane = tid & 63, wave = tid >> 6;
  int q = lane >> 4, ln = lane & 15;
  int rbase = blockIdx.y * 64 + wave * 16;
  union F8 { u32 u[4]; short8 s; };
  F8 af;
  {
    int r = rbase + ln;
#pragma unroll
    for (int i2 = 0; i2 < 4; ++i2)
      af.u[i2] = xls[(r << 4) | ((q * 4 + i2) ^ (r & 15))];
  }
  // --- S strip: acc[ct][reg] = S[rbase + q*4 + reg][ct*16 + ln] ---
  floatx4 acc[32];
#pragma unroll
  for (int ct = 0; ct < 32; ++ct) {
    int r2 = ct * 16 + ln;
    F8 bf;
#pragma unroll
    for (int i2 = 0; i2 < 4; ++i2)
      bf.u[i2] = xls[(r2 << 4) | ((q * 4 + i2) ^ (r2 & 15))];
    acc[ct] = __builtin_amdgcn_mfma_f32_16x16x32_bf16(af.s, bf.s,
              (floatx4){0.f, 0.f, 0.f, 0.f}, 0, 0, 0);
  }
  // mask cols 500..511 (ct=31, ln>=4)
  if (ln >= 4) {
#pragma unroll
    for (int i2 = 0; i2 < 4; ++i2) acc[31][i2] = -1e30f;
  }
  // --- softmax over 512 cols per row (scale folded into exp) ---
  const float sc = 0.17677669529663687f;
  float inv[4];
#pragma unroll
  for (int i2 = 0; i2 < 4; ++i2) {
    float m = -1e30f;
#pragma unroll
    for (int ct = 0; ct < 32; ++ct) m = fmaxf(m, acc[ct][i2]);
#pragma unroll
    for (int d = 1; d < 16; d <<= 1) m = fmaxf(m, __shfl_xor(m, d));
    float s = 0.f;
#pragma unroll
    for (int ct = 0; ct < 32; ++ct) {
      float e = expf((acc[ct][i2] - m) * sc);
      acc[ct][i2] = e; s += e;
    }
#pragma unroll
    for (int d = 1; d < 16; d <<= 1) s += __shfl_xor(s, d);
    inv[i2] = 1.f / s;
  }
  // --- PV: 16 K-chunks of 32; P via per-wave LDS round-trip to A-layout ---
  const float* vb = vals + bt * 16000;
  floatx4 zacc[2] = {{0.f,0.f,0.f,0.f},{0.f,0.f,0.f,0.f}};
  u32* myp = pch[wave];
  u16* pw = (u16*)myp;
  for (int c2 = 0; c2 < 16; ++c2) {
#pragma unroll
    for (int t2 = 0; t2 < 2; ++t2) {
      int ct = c2 * 2 + t2;
#pragma unroll
      for (int i2 = 0; i2 < 4; ++i2)
        pw[(q * 4 + i2) * 34 + t2 * 16 + ln] = f2b(acc[ct][i2] * inv[i2]);
    }
    __syncthreads();
    F8 pa;
#pragma unroll
    for (int i2 = 0; i2 < 4; ++i2) pa.u[i2] = myp[ln * 17 + q * 4 + i2];
    int k0 = c2 * 32 + q * 8;
#pragma unroll
    for (int t2 = 0; t2 < 2; ++t2) {
      int n = t2 * 16 + ln;
      short8 bs;
#pragma unroll
      for (int j = 0; j < 8; ++j) {
        float v = vb[(k0 + j) * 32 + n];      // rows >= 500 hit P==0 exactly -> contribute 0
        bs[j] = (short)(__float_as_uint(v) >> 16);
      }
      zacc[t2] = __builtin_amdgcn_mfma_f32_16x16x32_bf16(pa.s, bs, zacc[t2], 0, 0, 0);
    }
    __syncthreads();
  }
  // --- store Z (C layout: row = q*4+reg, col = t2*16+ln) ---
  int outb = bt * 16000;
#pragma unroll
  for (int t2 = 0; t2 < 2; ++t2) {
#pragma unroll
    for (int i2 = 0; i2 < 4; ++i2) {
      int r = rbase + q * 4 + i2;
      if (r < 500) outp[outb + r * 32 + t2 * 16 + ln] = zacc[t2][i2];
    }
  }
}

// ---------------- K4: mlp + gate + ct1 -> g2 ----------------
__global__ __launch_bounds__(256) void k_mlp(
    const float* __restrict__ h3x, const float* __restrict__ z1x, const float* __restrict__ z2x,
    const float* __restrict__ z3x, const float* __restrict__ z4x,
    const float* __restrict__ mlpW, const float* __restrict__ mlpB,
    const float* __restrict__ ct1W, const float* __restrict__ ct1B,
    float* __restrict__ g2w)
{
  __shared__ float Wm[10240];
  __shared__ float cat[32][161];
  __shared__ float ct1l[60];
  __shared__ float ct1bl[6];
  __shared__ float mbl[64];
  int tid = threadIdx.x;
  int b = blockIdx.y, n0 = blockIdx.x * 32;
  int nn = 500 - n0; if (nn > 32) nn = 32;
  for (int i = tid; i < 10240; i += 256) Wm[i] = mlpW[i];
  if (tid < 60) ct1l[tid] = ct1W[tid];
  if (tid < 6)  ct1bl[tid] = ct1B[tid];
  if (tid < 64) mbl[tid] = mlpB[tid];
  __syncthreads();
  int nl = tid & 31, slot = tid >> 5;
  bool act = nl < nn;
  int n = n0 + nl;
  float g2r[4][6];
#pragma unroll
  for (int k = 0; k < 4; ++k)
#pragma unroll
    for (int s = 0; s < 6; ++s) g2r[k][s] = 0.f;
  for (int t = 0; t < 10; ++t) {
    int rowbase = (b * 10 + t) * 500 + n0;
#pragma unroll
    for (int seg = 0; seg < 5; ++seg) {
      const float* sp = seg == 0 ? h3x : seg == 1 ? z1x : seg == 2 ? z2x : seg == 3 ? z3x : z4x;
      for (int i = tid; i < 1024; i += 256) {
        int nb = i >> 5, cc = i & 31;
        cat[nb][seg * 32 + cc] = (nb < nn) ? sp[(rowbase + nb) * 32 + cc] : 0.f;
      }
    }
    __syncthreads();
    if (act) {
      float hc[8];
#pragma unroll
      for (int k = 0; k < 8; ++k) hc[k] = mbl[slot + 8 * k];
      for (int cch = 0; cch < 160; ++cch) {
        float xvv = cat[nl][cch];
#pragma unroll
        for (int k = 0; k < 8; ++k) hc[k] += Wm[(slot + 8 * k) * 160 + cch] * xvv;
      }
#pragma unroll
      for (int k = 0; k < 4; ++k) {
        float gk = tanhf(hc[k]) * (1.f / (1.f + expf(-hc[k + 4])));
#pragma unroll
        for (int s = 0; s < 6; ++s) g2r[k][s] += gk * ct1l[s * 10 + t];
      }
    }
    __syncthreads();
  }
  if (act) {
#pragma unroll
    for (int k = 0; k < 4; ++k) {
      int cc = slot + 8 * k;
      int base = ((b * 32 + cc) * 500 + n) * 6;
#pragma unroll
      for (int s = 0; s < 6; ++s) g2w[base + s] = g2r[k][s] + ct1bl[s];
    }
  }
}

// ---------------- K4b: f1 ----------------
__global__ __launch_bounds__(256) void k_f1n(const float* __restrict__ g2w,
                                             const float* __restrict__ tc1W,
                                             float* __restrict__ f1w) {
  int i = blockIdx.x * 256 + threadIdx.x;
  if (i >= 48000) return;
  int b = i / 3000, rem = i - b * 3000, s = rem / 500, n = rem - s * 500;
  float a = 0.f;
  for (int c = 0; c < 32; ++c) a += g2w[((b * 32 + c) * 500 + n) * 6 + s] * tc1W[c];
  f1w[(b * 6 + s) * 500 + n] = a;
}

// ---------------- K5a: f2 ----------------
__global__ __launch_bounds__(64) void k_f2(const float* __restrict__ g2w,
                                           const float* __restrict__ c2W, float* __restrict__ f2w) {
  int b = blockIdx.x >> 5, c = blockIdx.x & 31, lane = threadIdx.x;
  float acc[6];
#pragma unroll
  for (int t = 0; t < 6; ++t) acc[t] = 0.f;
  for (int n = lane; n < 500; n += 64) {
    float w = c2W[n];
    const float* gp = g2w + ((b * 32 + c) * 500 + n) * 6;
#pragma unroll
    for (int t = 0; t < 6; ++t) acc[t] += w * gp[t];
  }
#pragma unroll
  for (int t = 0; t < 6; ++t)
    for (int off = 32; off; off >>= 1) acc[t] += __shfl_xor(acc[t], off);
  if (lane == 0) {
#pragma unroll
    for (int t = 0; t < 6; ++t) f2w[(b * 32 + c) * 6 + t] = acc[t];
  }
}

// ---------------- K5b: per-b TATT ----------------
__global__ __launch_bounds__(256) void k_tatt(
    const float* __restrict__ f1w, const float* __restrict__ tatw,
    const float* __restrict__ f2w, const float* __restrict__ tatb, const float* __restrict__ tatv,
    float* __restrict__ lg2w)
{
  __shared__ float mid[192];
  __shared__ float lgt[36];
  int b = blockIdx.x, tid = threadIdx.x;
  if (tid < 192) {
    int t = tid >> 5, c = tid & 31;
    float a = 0.f;
    const float* f1p = f1w + (b * 6 + t) * 500;
    for (int n = 0; n < 500; ++n) a += f1p[n] * tatw[n * 32 + c];
    mid[t * 32 + c] = a;
  }
  __syncthreads();
  if (tid < 36) {
    int t = tid / 6, s = tid - t * 6;
    float a = tatb[t * 6 + s];
    for (int c = 0; c < 32; ++c) a += mid[t * 32 + c] * f2w[(b * 32 + c) * 6 + s];
    lgt[t * 6 + s] = 1.f / (1.f + expf(-a));
  }
  __syncthreads();
  if (tid < 36) {
    int p = tid / 6, s = tid - p * 6;
    float a = 0.f;
#pragma unroll
    for (int t2 = 0; t2 < 6; ++t2) a += tatv[p * 6 + t2] * lgt[t2 * 6 + s];
    lg2w[(b * 6 + p) * 6 + s] = a;
  }
}

// ---------------- K5c: BN1 + softmax -> Tc ----------------
__global__ __launch_bounds__(128) void k_coefs(const float* __restrict__ lg2w,
    const float* __restrict__ bn1g, const float* __restrict__ bn1b, float* __restrict__ tcw) {
  __shared__ float mu[6], iv[6], gg[6], bb[6];
  int tid = threadIdx.x;
  if (tid < 6) {
    float s = 0.f, sq = 0.f;
    for (int b = 0; b < 16; ++b)
      for (int q = 0; q < 6; ++q) {
        float v = lg2w[(b * 6 + q) * 6 + tid];
        s += v; sq += v * v;
      }
    float m = s / 96.f;
    mu[tid] = m;
    iv[tid] = rsqrtf(sq / 96.f - m * m + 1e-5f);
    gg[tid] = bn1g[tid]; bb[tid] = bn1b[tid];
  }
  __syncthreads();
  for (int idx = tid; idx < 96; idx += 128) {
    int b = idx / 6, q = idx - b * 6;
    float v[6], mx = -1e30f;
#pragma unroll
    for (int l = 0; l < 6; ++l) {
      v[l] = (lg2w[(b * 6 + q) * 6 + l] - mu[l]) * iv[l] * gg[l] + bb[l];
      mx = fmaxf(mx, v[l]);
    }
    float tot = 0.f;
#pragma unroll
    for (int l = 0; l < 6; ++l) { v[l] = expf(v[l] - mx); tot += v[l]; }
    float inv = 1.f / tot;
#pragma unroll
    for (int l = 0; l < 6; ++l) tcw[(b * 6 + l) * 6 + q] = v[l] * inv;
  }
}

// ---------------- K6a: xo = leaky(g2@Tc)+res6, per-c sum/sumsq ----------------
__global__ __launch_bounds__(256) void k_xo(const float* __restrict__ g2w,
    const float* __restrict__ res6, const float* __restrict__ tcw,
    float* __restrict__ xow, float* __restrict__ stats) {
  __shared__ float Tcl[36];
  __shared__ float redS[32][8], redQ[32][8];
  int b = blockIdx.x, chunk = blockIdx.y, tid = threadIdx.x;
  if (tid < 36) Tcl[tid] = tcw[b * 36 + tid];
  __syncthreads();
  int c = tid & 31, sub = tid >> 5;
  int n0 = chunk * 50;
  float s = 0.f, sq = 0.f;
  for (int idx = sub; idx < 300; idx += 8) {
    int nl = idx / 6, q = idx - nl * 6;
    int n = n0 + nl;
    int base = ((b * 32 + c) * 500 + n) * 6;
    const float* gp = g2w + base;
    float xv = 0.f;
#pragma unroll
    for (int l = 0; l < 6; ++l) xv += gp[l] * Tcl[l * 6 + q];
    xv = xv > 0.f ? xv : 0.01f * xv;
    xv += res6[base + q];
    xow[base + q] = xv;
    s += xv; sq += xv * xv;
  }
  redS[c][sub] = s; redQ[c][sub] = sq;
  __syncthreads();
  if (sub == 0) {
    float ts = 0.f, tq = 0.f;
#pragma unroll
    for (int k = 0; k < 8; ++k) { ts += redS[c][k]; tq += redQ[c][k]; }
    atomicAdd(&stats[c], ts);
    atomicAdd(&stats[32 + c], tq);
  }
}

// ---------------- K6b: BN2 normalize -> FP32 out ----------------
__global__ __launch_bounds__(256) void k_out(const float* __restrict__ xow,
    const float* __restrict__ stats, const float* __restrict__ g2c, const float* __restrict__ b2c,
    float* __restrict__ out) {
  int base = (blockIdx.x * 256 + threadIdx.x) * 4;
#pragma unroll
  for (int k = 0; k < 4; ++k) {
    int i = base + k;
    int c = (i / 3000) & 31;
    float m = stats[c] * (1.f / 48000.f);
    float var = stats[32 + c] * (1.f / 48000.f) - m * m;
    out[i] = (xow[i] - m) * rsqrtf(var + 1e-5f) * g2c[c] + b2c[c];
  }
}

extern "C" void kernel_launch(void* const* d_in, const int* in_sizes, int n_in,
                              void* d_out, int out_size, void* d_ws, size_t ws_size,
                              hipStream_t stream)
{
  (void)in_sizes; (void)out_size;

  float* ws = (float*)d_ws;
  float* Af   = ws;                 // 250,000
  float* Wf   = Af + 250000;        // 65,536 (65,322 used)
  float* A2   = Wf + 65536;         // 250,000
  float* h3x  = A2 + 250000;        // 2,560,000 (B,T,N,32)
  float* z1x  = h3x + 2560000;
  float* z2x  = z1x + 2560000;
  float* z3x  = z2x + 2560000;
  float* z4x  = z3x + 2560000;
  float* res6 = z4x + 2560000;      // 1,536,000
  float* g2w  = res6 + 1536000;     // 1,536,000
  float* f1w  = g2w + 1536000;      // 48,000
  float* f2w  = f1w + 48000;        // 3,072
  float* lg2w = f2w + 3072;         // 576
  float* tcw  = lg2w + 576;         // 576
  float* stats= tcw + 576;          // 64
  int*   dtf  = (int*)(stats + 64); // 1 int
  float* xf   = z4x;                // x fp32 overlay: dead after k_front, before k_attn2#2
  float* xow  = z1x;                // reuse z1 region after k_mlp
  if (ws_size < (size_t)16489952 * sizeof(float)) return;  // workspace guard

  // converted-weight offsets inside Wf (cumulative over dict inputs 2..28)
  const float* c1W  = Wf + 0;
  const float* c1B  = Wf + 1024;
  const float* te1W = Wf + 1056;
  const float* te1B = Wf + 3104;
  const float* qW   = Wf + 3168;
  const float* qB   = Wf + 15456;
  const float* kW   = Wf + 15520;
  const float* kB   = Wf + 27808;
  const float* lvW  = Wf + 27872;
  const float* lvB  = Wf + 31968;
  const float* loW  = Wf + 32032;
  const float* loB  = Wf + 36128;
  const float* te2W = Wf + 36192;
  const float* te2B = Wf + 38240;
  const float* mlpW = Wf + 38272;
  const float* mlpB = Wf + 48512;
  const float* ct1W = Wf + 48576;
  const float* ct1B = Wf + 48636;
  const float* tc1W = Wf + 48642;
  const float* tc2W = Wf + 48674;
  const float* tatw = Wf + 49174;
  const float* tatb = Wf + 65174;
  const float* tatv = Wf + 65210;
  const float* bn1g = Wf + 65246;
  const float* bn1b = Wf + 65252;
  const float* bn2g = Wf + 65258;
  const float* bn2b = Wf + 65290;

  Ptrs ps;
  for (int i = 0; i < 29; ++i) ps.p[i] = (i < n_in) ? d_in[i] : d_in[0];

  hipMemsetAsync(stats, 0, 64 * sizeof(float), stream);
  k_resolve<<<dim3(1),     64, 0, stream>>>(ps.p[25], dtf);
  k_cvt  <<<dim3(1232),    256, 0, stream>>>(ps, dtf, Af, Wf);
  k_cvtx <<<dim3(10000),   256, 0, stream>>>(ps.p[0], dtf, xf);
  k_a2   <<<dim3(2, 63),   256, 0, stream>>>(Af, A2);
  k_front<<<dim3(63, 16),  256, 0, stream>>>(xf, c1W, c1B, te1W, te1B,
                                             qW, qB, kW, kB, lvW, lvB, loW, loB,
                                             te2W, te2B, h3x, res6);
  k_z12n <<<dim3(160, 63), 256, 0, stream>>>(h3x, Af, A2, z1x, z2x);
  k_attn2<<<dim3(160, 8),  256, 0, stream>>>(h3x, h3x, z3x);
  k_attn2<<<dim3(160, 8),  256, 0, stream>>>(h3x, z3x, z4x);
  k_mlp  <<<dim3(16, 16),  256, 0, stream>>>(h3x, z1x, z2x, z3x, z4x, mlpW, mlpB,
                                             ct1W, ct1B, g2w);
  k_f1n  <<<dim3(188),     256, 0, stream>>>(g2w, tc1W, f1w);
  k_f2   <<<dim3(512),      64, 0, stream>>>(g2w, tc2W, f2w);
  k_tatt <<<dim3(16),      256, 0, stream>>>(f1w, tatw, f2w, tatb, tatv, lg2w);
  k_coefs<<<dim3(1),       128, 0, stream>>>(lg2w, bn1g, bn1b, tcw);
  k_xo   <<<dim3(16, 10),  256, 0, stream>>>(g2w, res6, tcw, xow, stats);
  k_out  <<<dim3(1500),    256, 0, stream>>>(xow, stats, bn2g, bn2b, (float*)d_out);
}

// Round 10
// 1091.649 us; speedup vs baseline: 2.3408x; 1.3601x over previous
//
#include <hip/hip_runtime.h>

typedef unsigned short u16;
typedef unsigned int u32;

__device__ __forceinline__ float b2f(u16 v) { return __uint_as_float((u32)v << 16); }
__device__ __forceinline__ float lopart(u32 u) { return __uint_as_float(u << 16); }
__device__ __forceinline__ float hipart(u32 u) { return __uint_as_float(u & 0xffff0000u); }
__device__ __forceinline__ u16 f2b(float f) {
  u32 u = __float_as_uint(f);
  u32 r = u + 0x7fffu + ((u >> 16) & 1u);
  return (u16)(r >> 16);
}
__device__ __forceinline__ u32 pk2(float a, float b) {
  return (u32)f2b(a) | ((u32)f2b(b) << 16);
}

struct Ptrs { const void* p[29]; };

typedef __attribute__((ext_vector_type(8))) short short8;
typedef __attribute__((ext_vector_type(4))) float floatx4;

// ---------------- K-2: dtype flag (bn1_g[0]: bf16 pair 0x3F803F80 vs fp32 0x3F800000) ----------------
__global__ void k_resolve(const void* __restrict__ g1, int* __restrict__ dtf) {
  if (threadIdx.x == 0) {
    u32 w = *(const u32*)g1;
    *dtf = ((w & 0xffffu) != 0) ? 1 : 0;
  }
}

// ---------------- K-1: convert A + all weights to fp32 (C-order identity; dict order) ----------------
__global__ __launch_bounds__(256) void k_cvt(Ptrs ps, const int* __restrict__ dtf,
                                             float* __restrict__ Af, float* __restrict__ Wf) {
  bool BF = *dtf != 0;
  int i = blockIdx.x * 256 + threadIdx.x;
  if (i < 250000) {
    const void* pA = ps.p[1];
    Af[i] = BF ? b2f(((const u16*)pA)[i]) : ((const float*)pA)[i];
    return;
  }
  int j = i - 250000;
  if (j >= 65322) return;
  const int SZ[27] = {1024,32,2048,64,12288,64,12288,64,4096,64,4096,64,2048,32,
                      10240,64,60,6,32,500,16000,36,36,6,6,32,32};
  int t = 0, off = 0;
#pragma unroll
  for (int k = 0; k < 27; ++k) {
    if (t == k && j >= off + SZ[k]) { off += SZ[k]; t = k + 1; }
  }
  const void* src = ps.p[2 + t];
  int l = j - off;
  Wf[j] = BF ? b2f(((const u16*)src)[l]) : ((const float*)src)[l];
}

// ---------------- K-0b: x -> fp32 (identity C-order) ----------------
__global__ __launch_bounds__(256) void k_cvtx(const void* __restrict__ x, const int* __restrict__ dtf,
                                              float* __restrict__ xf) {
  bool BF = *dtf != 0;
  int i = blockIdx.x * 256 + threadIdx.x;
  if (i < 2560000) xf[i] = BF ? b2f(((const u16*)x)[i]) : ((const float*)x)[i];
}

// ---------------- K0: A2 = A @ A  (fp32) ----------------
__global__ __launch_bounds__(256) void k_a2(const float* __restrict__ Af, float* __restrict__ A2) {
  __shared__ float Arow[8][500];
  int tid = threadIdx.x;
  int j = blockIdx.x * 256 + tid;
  int i0 = blockIdx.y * 8;
  for (int i = tid; i < 4000; i += 256) {
    int r = i / 500, kk = i - r * 500;
    int ii = i0 + r; if (ii > 499) ii = 499;
    Arow[r][kk] = Af[ii * 500 + kk];
  }
  __syncthreads();
  if (j >= 500) return;
  float acc[8];
#pragma unroll
  for (int ii = 0; ii < 8; ++ii) acc[ii] = 0.f;
  for (int k = 0; k < 500; ++k) {
    float akj = Af[k * 500 + j];
#pragma unroll
    for (int ii = 0; ii < 8; ++ii) acc[ii] += Arow[ii][k] * akj;
  }
#pragma unroll
  for (int ii = 0; ii < 8; ++ii)
    if (i0 + ii < 500) A2[(i0 + ii) * 500 + j] = acc[ii];
}

// ---------------- K0b: pack A, A2 to zero-padded 512x512 bf16 ----------------
__global__ __launch_bounds__(256) void k_pk(const float* __restrict__ Af, const float* __restrict__ A2,
                                            u16* __restrict__ Abf, u16* __restrict__ A2bf) {
  int i = blockIdx.x * 256 + threadIdx.x;
  if (i >= 262144) return;
  int r = i >> 9, v = i & 511;
  bool in = (r < 500) && (v < 500);
  Abf[i]  = f2b(in ? Af[r * 500 + v] : 0.f);
  A2bf[i] = f2b(in ? A2[r * 500 + v] : 0.f);
}

// ---------------- K1: frontend  x -> h3x (B,T,N,32) + res6 ----------------
__global__ __launch_bounds__(256) void k_front(
    const float* __restrict__ xf,
    const float* __restrict__ c1W, const float* __restrict__ c1B,
    const float* __restrict__ te1W, const float* __restrict__ te1B,
    const float* __restrict__ qW, const float* __restrict__ qB,
    const float* __restrict__ kW, const float* __restrict__ kB,
    const float* __restrict__ lvW, const float* __restrict__ lvB,
    const float* __restrict__ loW, const float* __restrict__ loB,
    const float* __restrict__ te2W, const float* __restrict__ te2B,
    float* __restrict__ h3x, float* __restrict__ res6)
{
  __shared__ u32 qk[12288];          // packed (Wq | Wk<<16), layout [i][tap][o] (bank-spread)
  __shared__ float xv[32][10];
  __shared__ float h1b[64][10];
  __shared__ float qbuf[64][10];
  __shared__ float kbuf[64][10];
  __shared__ float vbuf[64][10];
  __shared__ float scb[800];
  int tid = threadIdx.x;
  int b = blockIdx.y;
  int n0 = blockIdx.x * 8;
  for (int e = tid; e < 12288; e += 256) {
    int i = e / 192, r2 = e - i * 192, kk = r2 >> 6, o = r2 & 63;
    int si = o * 192 + i * 3 + kk;
    qk[e] = pk2(qW[si], kW[si]);
  }
  __syncthreads();
  int nend = n0 + 8; if (nend > 500) nend = 500;
  for (int n = n0; n < nend; ++n) {
    for (int i = tid; i < 320; i += 256) {
      int c = i / 10, t = i - c * 10;
      xv[c][t] = xf[((b * 32 + c) * 500 + n) * 10 + t];
    }
    __syncthreads();
    if (tid < 192) {
      int c = tid / 6, t6 = tid - c * 6, t = t6 + 4;
      float a = c1B[c];
      for (int i = 0; i < 32; ++i) a += c1W[c * 32 + i] * xv[i][t];
      res6[((b * 32 + c) * 500 + n) * 6 + t6] = a;
    }
    for (int idx = tid; idx < 640; idx += 256) {
      int o = idx / 10, t = idx - o * 10;
      float a = te1B[o];
      for (int c = 0; c < 32; ++c) a += te1W[o * 32 + c] * xv[c][t];
      h1b[o][t] = a;
    }
    __syncthreads();
    for (int idx = tid; idx < 640; idx += 256) {
      int o = idx / 10, t = idx - o * 10;
      float aq = qB[o], ak = kB[o], av = lvB[o];
      int e = o;
      for (int i = 0; i < 64; ++i, e += 192) {
        float hm = (t > 0) ? h1b[i][t - 1] : 0.f;
        float h0 = h1b[i][t];
        float hp = (t < 9) ? h1b[i][t + 1] : 0.f;
        u32 u0 = qk[e], u1 = qk[e + 64], u2 = qk[e + 128];
        aq += lopart(u0) * hm + lopart(u1) * h0 + lopart(u2) * hp;
        ak += hipart(u0) * hm + hipart(u1) * h0 + hipart(u2) * hp;
        av += lvW[o * 64 + i] * h0;
      }
      qbuf[o][t] = aq; kbuf[o][t] = ak; vbuf[o][t] = av;
    }
    __syncthreads();
    for (int idx = tid; idx < 800; idx += 256) {
      int h = idx / 100, r = (idx / 10) % 10, s = idx - (idx / 10) * 10;
      float a = 0.f;
#pragma unroll
      for (int d = 0; d < 8; ++d) a += qbuf[h * 8 + d][r] * kbuf[h * 8 + d][s];
      scb[idx] = a * 0.35355339059327373f;
    }
    __syncthreads();
    if (tid < 80) {
      float* row = scb + tid * 10;
      float mx = row[0];
#pragma unroll
      for (int s = 1; s < 10; ++s) mx = fmaxf(mx, row[s]);
      float tot = 0.f;
#pragma unroll
      for (int s = 0; s < 10; ++s) { float e2 = expf(row[s] - mx); row[s] = e2; tot += e2; }
      float inv = 1.f / tot;
#pragma unroll
      for (int s = 0; s < 10; ++s) row[s] *= inv;
    }
    __syncthreads();
    for (int idx = tid; idx < 640; idx += 256) {
      int j = idx / 10, t = idx - j * 10, h = j >> 3;
      float a = 0.f;
#pragma unroll
      for (int s = 0; s < 10; ++s) a += scb[h * 100 + t * 10 + s] * vbuf[j][s];
      qbuf[j][t] = a;
    }
    __syncthreads();
    for (int idx = tid; idx < 640; idx += 256) {
      int o = idx / 10, t = idx - o * 10;
      float a = loB[o];
      for (int j = 0; j < 64; ++j) a += loW[o * 64 + j] * qbuf[j][t];
      kbuf[o][t] = a;
    }
    __syncthreads();
    for (int idx = tid; idx < 320; idx += 256) {
      int t = idx >> 5, c = idx & 31;
      float a = te2B[c];
      for (int j = 0; j < 64; ++j) a += te2W[c * 64 + j] * kbuf[j][t];
      h3x[((b * 10 + t) * 500 + n) * 32 + c] = a;
    }
    __syncthreads();
  }
}

// ---------------- K2: MFMA z1 = A @ XT, z2 = A2 @ XT ----------------
// Block = (bt, 64-row chunk), 4 waves; XT staged TRANSPOSED in LDS as bf16 pairs
// (4-u32-granular XOR swizzle -> conflict-free ds_read_b128 B-frags, shared by z1/z2).
// A/A2 frags read from L2-hot 512x512 bf16 packs.
__global__ __launch_bounds__(256, 4) void k_z12m(const float* __restrict__ h3x,
    const u16* __restrict__ Abf, const u16* __restrict__ A2bf,
    float* __restrict__ z1x, float* __restrict__ z2x) {
  __shared__ u32 xlsT[8192];     // [n][half-row] pairs, swizzled (32 KB)
  int tid = threadIdx.x, bt = blockIdx.x;
  const float* src = h3x + bt * 16000;
  for (int i = tid; i < 8192; i += 256) {
    int n = i & 31, h = i >> 5;
    int r0 = 2 * h;
    float v0 = (r0 < 500) ? src[r0 * 32 + n] : 0.f;
    float v1 = (r0 + 1 < 500) ? src[(r0 + 1) * 32 + n] : 0.f;
    xlsT[n * 256 + (((h & 0xFC) ^ ((n & 15) << 2)) | (h & 3))] = pk2(v0, v1);
  }
  __syncthreads();
  int lane = tid & 63, wave = tid >> 6;
  int q = lane >> 4, ln = lane & 15;
  int rbase = blockIdx.y * 64 + wave * 16;
  const u32* Au = (const u32*)Abf;
  const u32* A2u = (const u32*)A2bf;
  int arow = (rbase + ln) * 256;
  union F8 { u32 u[4]; short8 s; };
  floatx4 acc1[2] = {{0.f,0.f,0.f,0.f},{0.f,0.f,0.f,0.f}};
  floatx4 acc2[2] = {{0.f,0.f,0.f,0.f},{0.f,0.f,0.f,0.f}};
  for (int c2 = 0; c2 < 16; ++c2) {
    int hb = c2 * 16 + q * 4;         // aligned half-row base for this quad's k-slice
    F8 a1f, a2f;
#pragma unroll
    for (int i2 = 0; i2 < 4; ++i2) {
      a1f.u[i2] = Au[arow + hb + i2];
      a2f.u[i2] = A2u[arow + hb + i2];
    }
#pragma unroll
    for (int t2 = 0; t2 < 2; ++t2) {
      int n = t2 * 16 + ln;
      int baseT = n * 256 + (hb ^ ((n & 15) << 2));
      F8 bf;
#pragma unroll
      for (int i2 = 0; i2 < 4; ++i2) bf.u[i2] = xlsT[baseT + i2];
      acc1[t2] = __builtin_amdgcn_mfma_f32_16x16x32_bf16(a1f.s, bf.s, acc1[t2], 0, 0, 0);
      acc2[t2] = __builtin_amdgcn_mfma_f32_16x16x32_bf16(a2f.s, bf.s, acc2[t2], 0, 0, 0);
    }
  }
  int outb = bt * 16000;
#pragma unroll
  for (int t2 = 0; t2 < 2; ++t2) {
#pragma unroll
    for (int i2 = 0; i2 < 4; ++i2) {
      int r = rbase + q * 4 + i2;
      if (r < 500) {
        z1x[outb + r * 32 + t2 * 16 + ln] = acc1[t2][i2];
        z2x[outb + r * 32 + t2 * 16 + ln] = acc2[t2][i2];
      }
    }
  }
}

// ---------------- K3: MFMA fused attention: out = softmax(K K^T / sqrt(32)) @ V ----------------
__global__ __launch_bounds__(256, 2) void k_attn2(const float* __restrict__ keys,
                                                  const float* __restrict__ vals,
                                                  float* __restrict__ outp) {
  __shared__ u32 xls[8192];        // 512 rows x 16 u32 bf16-pairs, swizzled (32 KB)
  __shared__ u32 pch[4][272];      // per-wave P chunk: 16 x 17 u32 (4.25 KB)
  int tid = threadIdx.x, bt = blockIdx.x;
  const float* kb = keys + bt * 16000;
  for (int i = tid; i < 8192; i += 256) {
    int r = i >> 4, cu = i & 15;
    u32 u = 0;
    if (r < 500) {
      float2 g = *(const float2*)(kb + r * 32 + cu * 2);
      u = pk2(g.x, g.y);
    }
    xls[(r << 4) | (cu ^ (r & 15))] = u;
  }
  __syncthreads();
  int lane = tid & 63, wave = tid >> 6;
  int q = lane >> 4, ln = lane & 15;
  int rbase = blockIdx.y * 64 + wave * 16;
  union F8 { u32 u[4]; short8 s; };
  F8 af;
  {
    int r = rbase + ln;
#pragma unroll
    for (int i2 = 0; i2 < 4; ++i2)
      af.u[i2] = xls[(r << 4) | ((q * 4 + i2) ^ (r & 15))];
  }
  floatx4 acc[32];
#pragma unroll
  for (int ct = 0; ct < 32; ++ct) {
    int r2 = ct * 16 + ln;
    F8 bf;
#pragma unroll
    for (int i2 = 0; i2 < 4; ++i2)
      bf.u[i2] = xls[(r2 << 4) | ((q * 4 + i2) ^ (r2 & 15))];
    acc[ct] = __builtin_amdgcn_mfma_f32_16x16x32_bf16(af.s, bf.s,
              (floatx4){0.f, 0.f, 0.f, 0.f}, 0, 0, 0);
  }
  if (ln >= 4) {
#pragma unroll
    for (int i2 = 0; i2 < 4; ++i2) acc[31][i2] = -1e30f;
  }
  const float sc = 0.17677669529663687f;
  float inv[4];
#pragma unroll
  for (int i2 = 0; i2 < 4; ++i2) {
    float m = -1e30f;
#pragma unroll
    for (int ct = 0; ct < 32; ++ct) m = fmaxf(m, acc[ct][i2]);
#pragma unroll
    for (int d = 1; d < 16; d <<= 1) m = fmaxf(m, __shfl_xor(m, d));
    float s = 0.f;
#pragma unroll
    for (int ct = 0; ct < 32; ++ct) {
      float e = expf((acc[ct][i2] - m) * sc);
      acc[ct][i2] = e; s += e;
    }
#pragma unroll
    for (int d = 1; d < 16; d <<= 1) s += __shfl_xor(s, d);
    inv[i2] = 1.f / s;
  }
  const float* vb = vals + bt * 16000;
  floatx4 zacc[2] = {{0.f,0.f,0.f,0.f},{0.f,0.f,0.f,0.f}};
  u32* myp = pch[wave];
  u16* pw = (u16*)myp;
  for (int c2 = 0; c2 < 16; ++c2) {
#pragma unroll
    for (int t2 = 0; t2 < 2; ++t2) {
      int ct = c2 * 2 + t2;
#pragma unroll
      for (int i2 = 0; i2 < 4; ++i2)
        pw[(q * 4 + i2) * 34 + t2 * 16 + ln] = f2b(acc[ct][i2] * inv[i2]);
    }
    __syncthreads();
    F8 pa;
#pragma unroll
    for (int i2 = 0; i2 < 4; ++i2) pa.u[i2] = myp[ln * 17 + q * 4 + i2];
    int k0 = c2 * 32 + q * 8;
#pragma unroll
    for (int t2 = 0; t2 < 2; ++t2) {
      int n = t2 * 16 + ln;
      short8 bs;
#pragma unroll
      for (int j = 0; j < 8; ++j) {
        float v = vb[(k0 + j) * 32 + n];
        bs[j] = (short)(__float_as_uint(v) >> 16);
      }
      zacc[t2] = __builtin_amdgcn_mfma_f32_16x16x32_bf16(pa.s, bs, zacc[t2], 0, 0, 0);
    }
    __syncthreads();
  }
  int outb = bt * 16000;
#pragma unroll
  for (int t2 = 0; t2 < 2; ++t2) {
#pragma unroll
    for (int i2 = 0; i2 < 4; ++i2) {
      int r = rbase + q * 4 + i2;
      if (r < 500) outp[outb + r * 32 + t2 * 16 + ln] = zacc[t2][i2];
    }
  }
}

// ---------------- K4: mlp + gate + ct1 -> g2 ----------------
__global__ __launch_bounds__(256) void k_mlp(
    const float* __restrict__ h3x, const float* __restrict__ z1x, const float* __restrict__ z2x,
    const float* __restrict__ z3x, const float* __restrict__ z4x,
    const float* __restrict__ mlpW, const float* __restrict__ mlpB,
    const float* __restrict__ ct1W, const float* __restrict__ ct1B,
    float* __restrict__ g2w)
{
  __shared__ float Wm[10240];
  __shared__ float cat[32][161];
  __shared__ float ct1l[60];
  __shared__ float ct1bl[6];
  __shared__ float mbl[64];
  int tid = threadIdx.x;
  int b = blockIdx.y, n0 = blockIdx.x * 32;
  int nn = 500 - n0; if (nn > 32) nn = 32;
  for (int i = tid; i < 10240; i += 256) Wm[i] = mlpW[i];
  if (tid < 60) ct1l[tid] = ct1W[tid];
  if (tid < 6)  ct1bl[tid] = ct1B[tid];
  if (tid < 64) mbl[tid] = mlpB[tid];
  __syncthreads();
  int nl = tid & 31, slot = tid >> 5;
  bool act = nl < nn;
  int n = n0 + nl;
  float g2r[4][6];
#pragma unroll
  for (int k = 0; k < 4; ++k)
#pragma unroll
    for (int s = 0; s < 6; ++s) g2r[k][s] = 0.f;
  for (int t = 0; t < 10; ++t) {
    int rowbase = (b * 10 + t) * 500 + n0;
#pragma unroll
    for (int seg = 0; seg < 5; ++seg) {
      const float* sp = seg == 0 ? h3x : seg == 1 ? z1x : seg == 2 ? z2x : seg == 3 ? z3x : z4x;
      for (int i = tid; i < 1024; i += 256) {
        int nb = i >> 5, cc = i & 31;
        cat[nb][seg * 32 + cc] = (nb < nn) ? sp[(rowbase + nb) * 32 + cc] : 0.f;
      }
    }
    __syncthreads();
    if (act) {
      float hc[8];
#pragma unroll
      for (int k = 0; k < 8; ++k) hc[k] = mbl[slot + 8 * k];
      for (int cch = 0; cch < 160; ++cch) {
        float xvv = cat[nl][cch];
#pragma unroll
        for (int k = 0; k < 8; ++k) hc[k] += Wm[(slot + 8 * k) * 160 + cch] * xvv;
      }
#pragma unroll
      for (int k = 0; k < 4; ++k) {
        float gk = tanhf(hc[k]) * (1.f / (1.f + expf(-hc[k + 4])));
#pragma unroll
        for (int s = 0; s < 6; ++s) g2r[k][s] += gk * ct1l[s * 10 + t];
      }
    }
    __syncthreads();
  }
  if (act) {
#pragma unroll
    for (int k = 0; k < 4; ++k) {
      int cc = slot + 8 * k;
      int base = ((b * 32 + cc) * 500 + n) * 6;
#pragma unroll
      for (int s = 0; s < 6; ++s) g2w[base + s] = g2r[k][s] + ct1bl[s];
    }
  }
}

// ---------------- K4b: f1 ----------------
__global__ __launch_bounds__(256) void k_f1n(const float* __restrict__ g2w,
                                             const float* __restrict__ tc1W,
                                             float* __restrict__ f1w) {
  int i = blockIdx.x * 256 + threadIdx.x;
  if (i >= 48000) return;
  int b = i / 3000, rem = i - b * 3000, s = rem / 500, n = rem - s * 500;
  float a = 0.f;
  for (int c = 0; c < 32; ++c) a += g2w[((b * 32 + c) * 500 + n) * 6 + s] * tc1W[c];
  f1w[(b * 6 + s) * 500 + n] = a;
}

// ---------------- K5a: f2 ----------------
__global__ __launch_bounds__(64) void k_f2(const float* __restrict__ g2w,
                                           const float* __restrict__ c2W, float* __restrict__ f2w) {
  int b = blockIdx.x >> 5, c = blockIdx.x & 31, lane = threadIdx.x;
  float acc[6];
#pragma unroll
  for (int t = 0; t < 6; ++t) acc[t] = 0.f;
  for (int n = lane; n < 500; n += 64) {
    float w = c2W[n];
    const float* gp = g2w + ((b * 32 + c) * 500 + n) * 6;
#pragma unroll
    for (int t = 0; t < 6; ++t) acc[t] += w * gp[t];
  }
#pragma unroll
  for (int t = 0; t < 6; ++t)
    for (int off = 32; off; off >>= 1) acc[t] += __shfl_xor(acc[t], off);
  if (lane == 0) {
#pragma unroll
    for (int t = 0; t < 6; ++t) f2w[(b * 32 + c) * 6 + t] = acc[t];
  }
}

// ---------------- K5b: per-b TATT ----------------
__global__ __launch_bounds__(256) void k_tatt(
    const float* __restrict__ f1w, const float* __restrict__ tatw,
    const float* __restrict__ f2w, const float* __restrict__ tatb, const float* __restrict__ tatv,
    float* __restrict__ lg2w)
{
  __shared__ float mid[192];
  __shared__ float lgt[36];
  int b = blockIdx.x, tid = threadIdx.x;
  if (tid < 192) {
    int t = tid >> 5, c = tid & 31;
    float a = 0.f;
    const float* f1p = f1w + (b * 6 + t) * 500;
    for (int n = 0; n < 500; ++n) a += f1p[n] * tatw[n * 32 + c];
    mid[t * 32 + c] = a;
  }
  __syncthreads();
  if (tid < 36) {
    int t = tid / 6, s = tid - t * 6;
    float a = tatb[t * 6 + s];
    for (int c = 0; c < 32; ++c) a += mid[t * 32 + c] * f2w[(b * 32 + c) * 6 + s];
    lgt[t * 6 + s] = 1.f / (1.f + expf(-a));
  }
  __syncthreads();
  if (tid < 36) {
    int p = tid / 6, s = tid - p * 6;
    float a = 0.f;
#pragma unroll
    for (int t2 = 0; t2 < 6; ++t2) a += tatv[p * 6 + t2] * lgt[t2 * 6 + s];
    lg2w[(b * 6 + p) * 6 + s] = a;
  }
}

// ---------------- K5c: BN1 + softmax -> Tc ----------------
__global__ __launch_bounds__(128) void k_coefs(const float* __restrict__ lg2w,
    const float* __restrict__ bn1g, const float* __restrict__ bn1b, float* __restrict__ tcw) {
  __shared__ float mu[6], iv[6], gg[6], bb[6];
  int tid = threadIdx.x;
  if (tid < 6) {
    float s = 0.f, sq = 0.f;
    for (int b = 0; b < 16; ++b)
      for (int q = 0; q < 6; ++q) {
        float v = lg2w[(b * 6 + q) * 6 + tid];
        s += v; sq += v * v;
      }
    float m = s / 96.f;
    mu[tid] = m;
    iv[tid] = rsqrtf(sq / 96.f - m * m + 1e-5f);
    gg[tid] = bn1g[tid]; bb[tid] = bn1b[tid];
  }
  __syncthreads();
  for (int idx = tid; idx < 96; idx += 128) {
    int b = idx / 6, q = idx - b * 6;
    float v[6], mx = -1e30f;
#pragma unroll
    for (int l = 0; l < 6; ++l) {
      v[l] = (lg2w[(b * 6 + q) * 6 + l] - mu[l]) * iv[l] * gg[l] + bb[l];
      mx = fmaxf(mx, v[l]);
    }
    float tot = 0.f;
#pragma unroll
    for (int l = 0; l < 6; ++l) { v[l] = expf(v[l] - mx); tot += v[l]; }
    float inv = 1.f / tot;
#pragma unroll
    for (int l = 0; l < 6; ++l) tcw[(b * 6 + l) * 6 + q] = v[l] * inv;
  }
}

// ---------------- K6a: xo = leaky(g2@Tc)+res6, per-c sum/sumsq ----------------
__global__ __launch_bounds__(256) void k_xo(const float* __restrict__ g2w,
    const float* __restrict__ res6, const float* __restrict__ tcw,
    float* __restrict__ xow, float* __restrict__ stats) {
  __shared__ float Tcl[36];
  __shared__ float redS[32][8], redQ[32][8];
  int b = blockIdx.x, chunk = blockIdx.y, tid = threadIdx.x;
  if (tid < 36) Tcl[tid] = tcw[b * 36 + tid];
  __syncthreads();
  int c = tid & 31, sub = tid >> 5;
  int n0 = chunk * 50;
  float s = 0.f, sq = 0.f;
  for (int idx = sub; idx < 300; idx += 8) {
    int nl = idx / 6, q = idx - nl * 6;
    int n = n0 + nl;
    int base = ((b * 32 + c) * 500 + n) * 6;
    const float* gp = g2w + base;
    float xv = 0.f;
#pragma unroll
    for (int l = 0; l < 6; ++l) xv += gp[l] * Tcl[l * 6 + q];
    xv = xv > 0.f ? xv : 0.01f * xv;
    xv += res6[base + q];
    xow[base + q] = xv;
    s += xv; sq += xv * xv;
  }
  redS[c][sub] = s; redQ[c][sub] = sq;
  __syncthreads();
  if (sub == 0) {
    float ts = 0.f, tq = 0.f;
#pragma unroll
    for (int k = 0; k < 8; ++k) { ts += redS[c][k]; tq += redQ[c][k]; }
    atomicAdd(&stats[c], ts);
    atomicAdd(&stats[32 + c], tq);
  }
}

// ---------------- K6b: BN2 normalize -> FP32 out ----------------
__global__ __launch_bounds__(256) void k_out(const float* __restrict__ xow,
    const float* __restrict__ stats, const float* __restrict__ g2c, const float* __restrict__ b2c,
    float* __restrict__ out) {
  int base = (blockIdx.x * 256 + threadIdx.x) * 4;
#pragma unroll
  for (int k = 0; k < 4; ++k) {
    int i = base + k;
    int c = (i / 3000) & 31;
    float m = stats[c] * (1.f / 48000.f);
    float var = stats[32 + c] * (1.f / 48000.f) - m * m;
    out[i] = (xow[i] - m) * rsqrtf(var + 1e-5f) * g2c[c] + b2c[c];
  }
}

extern "C" void kernel_launch(void* const* d_in, const int* in_sizes, int n_in,
                              void* d_out, int out_size, void* d_ws, size_t ws_size,
                              hipStream_t stream)
{
  (void)in_sizes; (void)out_size;

  float* ws = (float*)d_ws;
  float* Af   = ws;                 // 250,000
  float* Wf   = Af + 250000;        // 65,536 (65,322 used)
  float* A2   = Wf + 65536;         // 250,000
  float* h3x  = A2 + 250000;        // 2,560,000 (B,T,N,32)
  float* z1x  = h3x + 2560000;
  float* z2x  = z1x + 2560000;
  float* z3x  = z2x + 2560000;
  float* z4x  = z3x + 2560000;
  float* res6 = z4x + 2560000;      // 1,536,000
  float* g2w  = res6 + 1536000;     // 1,536,000
  float* f1w  = g2w + 1536000;      // 48,000
  float* f2w  = f1w + 48000;        // 3,072
  float* lg2w = f2w + 3072;         // 576
  float* tcw  = lg2w + 576;         // 576
  float* stats= tcw + 576;          // 64
  int*   dtf  = (int*)(stats + 64); // 1 int
  float* xf   = z4x;                // x fp32 overlay: dead after k_front, before k_attn2#2
  float* xow  = z1x;                // reuse z1 region after k_mlp
  u16*   Abf  = (u16*)g2w;          // 512x512 bf16 A pack (g2w region dead until k_mlp)
  u16*   A2bf = (u16*)(g2w + 131072); // 512x512 bf16 A2 pack
  if (ws_size < (size_t)16489952 * sizeof(float)) return;  // workspace guard

  // converted-weight offsets inside Wf (cumulative over dict inputs 2..28)
  const float* c1W  = Wf + 0;
  const float* c1B  = Wf + 1024;
  const float* te1W = Wf + 1056;
  const float* te1B = Wf + 3104;
  const float* qW   = Wf + 3168;
  const float* qB   = Wf + 15456;
  const float* kW   = Wf + 15520;
  const float* kB   = Wf + 27808;
  const float* lvW  = Wf + 27872;
  const float* lvB  = Wf + 31968;
  const float* loW  = Wf + 32032;
  const float* loB  = Wf + 36128;
  const float* te2W = Wf + 36192;
  const float* te2B = Wf + 38240;
  const float* mlpW = Wf + 38272;
  const float* mlpB = Wf + 48512;
  const float* ct1W = Wf + 48576;
  const float* ct1B = Wf + 48636;
  const float* tc1W = Wf + 48642;
  const float* tc2W = Wf + 48674;
  const float* tatw = Wf + 49174;
  const float* tatb = Wf + 65174;
  const float* tatv = Wf + 65210;
  const float* bn1g = Wf + 65246;
  const float* bn1b = Wf + 65252;
  const float* bn2g = Wf + 65258;
  const float* bn2b = Wf + 65290;

  Ptrs ps;
  for (int i = 0; i < 29; ++i) ps.p[i] = (i < n_in) ? d_in[i] : d_in[0];

  hipMemsetAsync(stats, 0, 64 * sizeof(float), stream);
  k_resolve<<<dim3(1),     64, 0, stream>>>(ps.p[25], dtf);
  k_cvt  <<<dim3(1232),    256, 0, stream>>>(ps, dtf, Af, Wf);
  k_cvtx <<<dim3(10000),   256, 0, stream>>>(ps.p[0], dtf, xf);
  k_a2   <<<dim3(2, 63),   256, 0, stream>>>(Af, A2);
  k_pk   <<<dim3(1024),    256, 0, stream>>>(Af, A2, Abf, A2bf);
  k_front<<<dim3(63, 16),  256, 0, stream>>>(xf, c1W, c1B, te1W, te1B,
                                             qW, qB, kW, kB, lvW, lvB, loW, loB,
                                             te2W, te2B, h3x, res6);
  k_z12m <<<dim3(160, 8),  256, 0, stream>>>(h3x, Abf, A2bf, z1x, z2x);
  k_attn2<<<dim3(160, 8),  256, 0, stream>>>(h3x, h3x, z3x);
  k_attn2<<<dim3(160, 8),  256, 0, stream>>>(h3x, z3x, z4x);
  k_mlp  <<<dim3(16, 16),  256, 0, stream>>>(h3x, z1x, z2x, z3x, z4x, mlpW, mlpB,
                                             ct1W, ct1B, g2w);
  k_f1n  <<<dim3(188),     256, 0, stream>>>(g2w, tc1W, f1w);
  k_f2   <<<dim3(512),      64, 0, stream>>>(g2w, tc2W, f2w);
  k_tatt <<<dim3(16),      256, 0, stream>>>(f1w, tatw, f2w, tatb, tatv, lg2w);
  k_coefs<<<dim3(1),       128, 0, stream>>>(lg2w, bn1g, bn1b, tcw);
  k_xo   <<<dim3(16, 10),  256, 0, stream>>>(g2w, res6, tcw, xow, stats);
  k_out  <<<dim3(1500),    256, 0, stream>>>(xow, stats, bn2g, bn2b, (float*)d_out);
}